// Round 1
// baseline (822.867 us; speedup 1.0000x reference)
//
#include <hip/hip_runtime.h>
#include <math.h>

#define B_ 16
#define N_ 4096
#define KP1 17          // K+1 smallest, includes self (dist 0)
#define ALPHA_ 1.05f
#define BLK 128         // threads per block for knn kernel
#define TILES (N_ / BLK)

// ---------------------------------------------------------------------------
// Kernel 1: per-point mean of 16 smallest non-self squared distances.
// One thread = one point i. Whole batch cloud staged SoA in LDS (48 KB).
// All lanes read the same cloud[j] each iteration -> LDS broadcast (free).
// Top-17 kept in a sorted register array (static indices, fully unrolled).
// ---------------------------------------------------------------------------
__global__ __launch_bounds__(BLK) void knn_kernel(const float* __restrict__ pcs,
                                                  float* __restrict__ knn_out) {
    __shared__ float cx[N_];
    __shared__ float cy[N_];
    __shared__ float cz[N_];

    const int b    = blockIdx.x / TILES;
    const int tile = blockIdx.x % TILES;
    const int tid  = threadIdx.x;

    const float* __restrict__ src = pcs + (size_t)b * N_ * 3;
    for (int j = tid; j < N_; j += BLK) {
        cx[j] = src[3 * j + 0];
        cy[j] = src[3 * j + 1];
        cz[j] = src[3 * j + 2];
    }
    __syncthreads();

    const int i = tile * BLK + tid;
    const float mx = cx[i], my = cy[i], mz = cz[i];

    float knn[KP1];
#pragma unroll
    for (int t = 0; t < KP1; ++t) knn[t] = 3.0e38f;

    for (int j = 0; j < N_; ++j) {
        const float dx = mx - cx[j];
        const float dy = my - cy[j];
        const float dz = mz - cz[j];
        const float d  = dx * dx + dy * dy + dz * dz;
        if (d < knn[KP1 - 1]) {
            knn[KP1 - 1] = d;
#pragma unroll
            for (int t = KP1 - 1; t > 0; --t) {
                const float a = knn[t - 1];
                const float c = knn[t];
                knn[t - 1] = fminf(a, c);
                knn[t]     = fmaxf(a, c);
            }
        }
    }

    // knn[0] is the self distance (exactly 0, the unique minimum for random
    // data); reference drops the smallest of the K+1. Sum knn[1..16].
    float s = 0.0f;
#pragma unroll
    for (int t = 1; t < KP1; ++t) s += knn[t];
    knn_out[b * N_ + i] = s * (1.0f / 16.0f);
}

// ---------------------------------------------------------------------------
// Block reduction helper (256 threads = 4 waves)
// ---------------------------------------------------------------------------
__device__ __forceinline__ float block_reduce_sum_256(float v, float* sbuf) {
    const int lane = threadIdx.x & 63;
    const int w    = threadIdx.x >> 6;
#pragma unroll
    for (int o = 32; o > 0; o >>= 1) v += __shfl_down(v, o, 64);
    __syncthreads();               // protect sbuf reuse across calls
    if (lane == 0) sbuf[w] = v;
    __syncthreads();
    return sbuf[0] + sbuf[1] + sbuf[2] + sbuf[3];
}

// ---------------------------------------------------------------------------
// Kernel 2: per-batch mean, std (two-pass), threshold, penalty partial sum.
// One block (256 threads) per batch; 16 values per thread in registers.
// ---------------------------------------------------------------------------
__global__ __launch_bounds__(256) void stats_kernel(const float* __restrict__ knn_d,
                                                    float* __restrict__ partial) {
    const int b   = blockIdx.x;
    const int tid = threadIdx.x;
    const float* __restrict__ x = knn_d + (size_t)b * N_;

    __shared__ float sbuf[4];

    float v[16];
    float s = 0.0f;
#pragma unroll
    for (int t = 0; t < 16; ++t) {
        v[t] = x[tid + t * 256];
        s += v[t];
    }
    const float total = block_reduce_sum_256(s, sbuf);
    const float mu = total * (1.0f / (float)N_);

    float vs = 0.0f;
#pragma unroll
    for (int t = 0; t < 16; ++t) {
        const float d = v[t] - mu;
        vs += d * d;
    }
    const float var    = block_reduce_sum_256(vs, sbuf) * (1.0f / (float)N_);
    const float thresh = mu + ALPHA_ * sqrtf(var);

    float p = 0.0f;
#pragma unroll
    for (int t = 0; t < 16; ++t) {
        if (v[t] > thresh) p += v[t];
    }
    const float psum = block_reduce_sum_256(p, sbuf);
    if (tid == 0) partial[b] = psum;
}

// ---------------------------------------------------------------------------
// Kernel 3: final scalar = sum(partial) / (B*N)
// ---------------------------------------------------------------------------
__global__ void final_kernel(const float* __restrict__ partial,
                             float* __restrict__ out) {
    if (threadIdx.x == 0) {
        float s = 0.0f;
#pragma unroll
        for (int b = 0; b < B_; ++b) s += partial[b];
        out[0] = s / (float)(B_ * N_);
    }
}

extern "C" void kernel_launch(void* const* d_in, const int* in_sizes, int n_in,
                              void* d_out, int out_size, void* d_ws, size_t ws_size,
                              hipStream_t stream) {
    const float* pcs = (const float*)d_in[0];
    float* out = (float*)d_out;

    float* knn_d   = (float*)d_ws;           // B*N floats = 256 KB
    float* partial = knn_d + B_ * N_;        // B floats

    knn_kernel<<<B_ * TILES, BLK, 0, stream>>>(pcs, knn_d);
    stats_kernel<<<B_, 256, 0, stream>>>(knn_d, partial);
    final_kernel<<<1, 64, 0, stream>>>(partial, out);
}

// Round 2
// 400.375 us; speedup vs baseline: 2.0552x; 2.0552x over previous
//
#include <hip/hip_runtime.h>
#include <math.h>

#define B_ 16
#define N_ 4096
#define K_ 16
#define ALPHA_ 1.05f

#define JSPLIT 4            // j-chunks per point (one wave each)
#define CHUNK (N_ / JSPLIT) // 1024 j's per wave
#define TJ 256              // j-tile staged in LDS per wave
#define PTS 64              // points per block (one per lane)
#define BLK 256             // 4 waves

// ---------------------------------------------------------------------------
// Kernel 1: per-point mean of 16 smallest non-self squared distances.
// Block = 256 threads = 4 waves. Wave w handles points [i0, i0+64) against
// j-chunk w (1024 j's), keeping a per-lane sorted top-16 in registers.
// Each wave stages its own 256-j tile in LDS as float4 (one broadcast
// ds_read_b128 per j). Self excluded via jg != i predicate. After the main
// loop, 4 sorted 16-lists per point are merged by one thread per point.
// ---------------------------------------------------------------------------
__global__ __launch_bounds__(BLK, 4) void knn_kernel(const float* __restrict__ pcs,
                                                     float* __restrict__ knn_out) {
    __shared__ float4 tile[JSPLIT][TJ];      // 16 KB, wave-private quadrants
    __shared__ float  lst[JSPLIT][PTS][K_ + 1]; // 17 KB, +1 pad: bank + sentinel

    const int b    = blockIdx.x >> 6;        // 64 blocks per batch
    const int grp  = blockIdx.x & 63;
    const int i0   = grp * PTS;
    const int lane = threadIdx.x & 63;
    const int w    = threadIdx.x >> 6;

    const float* __restrict__ src = pcs + (size_t)b * N_ * 3;

    // this lane's query point
    const int i  = i0 + lane;
    const float mx = src[3 * i + 0];
    const float my = src[3 * i + 1];
    const float mz = src[3 * i + 2];

    float knn[K_];
#pragma unroll
    for (int t = 0; t < K_; ++t) knn[t] = 3.0e38f;

    const int jbase = w * CHUNK;
    float* tileF = (float*)&tile[w][0];

    for (int t0 = 0; t0 < CHUNK; t0 += TJ) {
        // ---- stage TJ points (768 floats) into this wave's LDS quadrant,
        //      padded to float4 (x,y,z,_). Writes are conflict-free reads of
        //      768 consecutive floats; scatter writes <=3-way conflict.
        const float* __restrict__ g = src + (size_t)(jbase + t0) * 3;
#pragma unroll
        for (int m = 0; m < (TJ * 3) / 64; ++m) {
            const int f = lane + 64 * m;
            tileF[(f / 3) * 4 + (f % 3)] = g[f];
        }
        // same-wave LDS write->read ordering: compiler inserts lgkmcnt waits
        // (may-alias); lanes are lockstep within the wave, no barrier needed.

        const int jg0 = jbase + t0;
#pragma unroll 4
        for (int jj = 0; jj < TJ; ++jj) {
            const float4 p = tile[w][jj];          // uniform -> LDS broadcast
            const float dx = mx - p.x;
            const float dy = my - p.y;
            const float dz = mz - p.z;
            const float d  = fmaf(dx, dx, fmaf(dy, dy, dz * dz));
            const int  jg  = jg0 + jj;
            if (d < knn[K_ - 1] && jg != i) {
                knn[K_ - 1] = d;
#pragma unroll
                for (int t = K_ - 1; t > 0; --t) {
                    const float a = knn[t - 1];
                    const float c = knn[t];
                    knn[t - 1] = fminf(a, c);
                    knn[t]     = fmaxf(a, c);
                }
            }
        }
    }

    // ---- publish sorted list + sentinel
#pragma unroll
    for (int q = 0; q < K_; ++q) lst[w][lane][q] = knn[q];
    lst[w][lane][K_] = 3.0e38f;
    __syncthreads();

    // ---- 4-way merge of sorted lists, one thread per point (wave 0)
    if (threadIdx.x < PTS) {
        const int l = threadIdx.x;
        int p0 = 0, p1 = 0, p2 = 0, p3 = 0;
        float h0 = lst[0][l][0], h1 = lst[1][l][0];
        float h2 = lst[2][l][0], h3 = lst[3][l][0];
        float s = 0.0f;
#pragma unroll
        for (int step = 0; step < K_; ++step) {
            const float m = fminf(fminf(h0, h1), fminf(h2, h3));
            s += m;
            if (h0 == m)      { h0 = lst[0][l][++p0]; }
            else if (h1 == m) { h1 = lst[1][l][++p1]; }
            else if (h2 == m) { h2 = lst[2][l][++p2]; }
            else              { h3 = lst[3][l][++p3]; }
        }
        knn_out[b * N_ + i0 + l] = s * (1.0f / (float)K_);
    }
}

// ---------------------------------------------------------------------------
// Block reduction helper (256 threads = 4 waves)
// ---------------------------------------------------------------------------
__device__ __forceinline__ float block_reduce_sum_256(float v, float* sbuf) {
    const int lane = threadIdx.x & 63;
    const int w    = threadIdx.x >> 6;
#pragma unroll
    for (int o = 32; o > 0; o >>= 1) v += __shfl_down(v, o, 64);
    __syncthreads();
    if (lane == 0) sbuf[w] = v;
    __syncthreads();
    return sbuf[0] + sbuf[1] + sbuf[2] + sbuf[3];
}

// ---------------------------------------------------------------------------
// Kernel 2: per-batch mean, std (two-pass), threshold, penalty partial sum.
// ---------------------------------------------------------------------------
__global__ __launch_bounds__(256) void stats_kernel(const float* __restrict__ knn_d,
                                                    float* __restrict__ partial) {
    const int b   = blockIdx.x;
    const int tid = threadIdx.x;
    const float* __restrict__ x = knn_d + (size_t)b * N_;

    __shared__ float sbuf[4];

    float v[16];
    float s = 0.0f;
#pragma unroll
    for (int t = 0; t < 16; ++t) {
        v[t] = x[tid + t * 256];
        s += v[t];
    }
    const float total = block_reduce_sum_256(s, sbuf);
    const float mu = total * (1.0f / (float)N_);

    float vs = 0.0f;
#pragma unroll
    for (int t = 0; t < 16; ++t) {
        const float d = v[t] - mu;
        vs += d * d;
    }
    const float var    = block_reduce_sum_256(vs, sbuf) * (1.0f / (float)N_);
    const float thresh = mu + ALPHA_ * sqrtf(var);

    float p = 0.0f;
#pragma unroll
    for (int t = 0; t < 16; ++t) {
        if (v[t] > thresh) p += v[t];
    }
    const float psum = block_reduce_sum_256(p, sbuf);
    if (tid == 0) partial[b] = psum;
}

// ---------------------------------------------------------------------------
// Kernel 3: final scalar = sum(partial) / (B*N)
// ---------------------------------------------------------------------------
__global__ void final_kernel(const float* __restrict__ partial,
                             float* __restrict__ out) {
    if (threadIdx.x == 0) {
        float s = 0.0f;
#pragma unroll
        for (int b = 0; b < B_; ++b) s += partial[b];
        out[0] = s / (float)(B_ * N_);
    }
}

extern "C" void kernel_launch(void* const* d_in, const int* in_sizes, int n_in,
                              void* d_out, int out_size, void* d_ws, size_t ws_size,
                              hipStream_t stream) {
    const float* pcs = (const float*)d_in[0];
    float* out = (float*)d_out;

    float* knn_d   = (float*)d_ws;           // B*N floats = 256 KB
    float* partial = knn_d + B_ * N_;        // B floats

    knn_kernel<<<B_ * (N_ / PTS), BLK, 0, stream>>>(pcs, knn_d);
    stats_kernel<<<B_, 256, 0, stream>>>(knn_d, partial);
    final_kernel<<<1, 64, 0, stream>>>(partial, out);
}

// Round 3
// 188.751 us; speedup vs baseline: 4.3595x; 2.1212x over previous
//
#include <hip/hip_runtime.h>
#include <math.h>

#define B_ 16
#define N_ 4096
#define K_ 16
#define ALPHA_ 1.05f

#define JSPLIT 4            // j-chunks per point (one wave each)
#define CHUNK (N_ / JSPLIT) // 1024 j's per wave
#define TJ 256              // j-tile staged in LDS per wave
#define PTS 64              // points per block (one per lane)
#define BLK 256             // 4 waves
#define HUGE_D 1.0e30f

// ---------------------------------------------------------------------------
// Branch-free helpers: bitonic networks on 16 registers (static indices only).
// ---------------------------------------------------------------------------
__device__ __forceinline__ void bitonic_sort16(float v[16]) {
#pragma unroll
    for (int k = 2; k <= 16; k <<= 1) {
#pragma unroll
        for (int j = k >> 1; j > 0; j >>= 1) {
#pragma unroll
            for (int i = 0; i < 16; ++i) {
                const int l = i ^ j;
                if (l > i) {
                    const bool up = ((i & k) == 0);   // compile-time
                    const float a = v[i], b = v[l];
                    const float lo = fminf(a, b), hi = fmaxf(a, b);
                    v[i] = up ? lo : hi;
                    v[l] = up ? hi : lo;
                }
            }
        }
    }
}

// knn (sorted asc) := lowest 16 of {knn, c} where c is sorted asc.
__device__ __forceinline__ void merge16(float knn[16], const float c[16]) {
#pragma unroll
    for (int i = 0; i < 16; ++i) knn[i] = fminf(knn[i], c[15 - i]);
    // knn is now bitonic; finish with an ascending bitonic merge
#pragma unroll
    for (int j = 8; j > 0; j >>= 1) {
#pragma unroll
        for (int i = 0; i < 16; ++i) {
            const int l = i ^ j;
            if (l > i) {
                const float a = knn[i], b = knn[l];
                knn[i] = fminf(a, b);
                knn[l] = fmaxf(a, b);
            }
        }
    }
}

// ---------------------------------------------------------------------------
// Process one 256-j LDS tile: 16 batches of 16 distances -> sort -> merge.
// HAS_SELF is wave-uniform (true only for the tile containing this block's
// own 64 points).
// ---------------------------------------------------------------------------
template <bool HAS_SELF>
__device__ __forceinline__ void process_tile(const float4* __restrict__ tile,
                                             int jg0, int i,
                                             float mx, float my, float mz,
                                             float knn[16]) {
#pragma unroll 1
    for (int bb = 0; bb < TJ / 16; ++bb) {
        float d[16];
#pragma unroll
        for (int jj = 0; jj < 16; ++jj) {
            const float4 p = tile[bb * 16 + jj];   // uniform -> LDS broadcast
            const float dx = mx - p.x;
            const float dy = my - p.y;
            const float dz = mz - p.z;
            float dd = fmaf(dx, dx, fmaf(dy, dy, dz * dz));
            if (HAS_SELF) {
                const int jg = jg0 + bb * 16 + jj;
                dd = (jg == i) ? HUGE_D : dd;
            }
            d[jj] = dd;
        }
        bitonic_sort16(d);
        merge16(knn, d);
    }
}

// ---------------------------------------------------------------------------
// Kernel 1: per-point mean of 16 smallest non-self squared distances.
// Block = 256 threads = 4 waves. Wave w handles points [i0, i0+64) against
// j-chunk w (1024 j's). Selection is fully branch-free (bitonic batch merge).
// ---------------------------------------------------------------------------
__global__ __launch_bounds__(BLK, 4) void knn_kernel(const float* __restrict__ pcs,
                                                     float* __restrict__ knn_out) {
    __shared__ float4 tile[JSPLIT][TJ];          // 16 KB, wave-private quadrants
    __shared__ float  lst[JSPLIT][PTS][K_ + 1];  // 17 KB, +1 pad: bank + sentinel

    const int b    = blockIdx.x >> 6;            // 64 blocks per batch
    const int grp  = blockIdx.x & 63;
    const int i0   = grp * PTS;
    const int lane = threadIdx.x & 63;
    const int w    = threadIdx.x >> 6;

    const float* __restrict__ src = pcs + (size_t)b * N_ * 3;

    const int i  = i0 + lane;
    const float mx = src[3 * i + 0];
    const float my = src[3 * i + 1];
    const float mz = src[3 * i + 2];

    float knn[K_];
#pragma unroll
    for (int t = 0; t < K_; ++t) knn[t] = HUGE_D;

    const int jbase = w * CHUNK;
    float* tileF = (float*)&tile[w][0];

    for (int t0 = 0; t0 < CHUNK; t0 += TJ) {
        // ---- stage TJ points (768 floats) into this wave's LDS quadrant,
        //      padded to float4 (x,y,z,_).
        const float* __restrict__ g = src + (size_t)(jbase + t0) * 3;
#pragma unroll
        for (int m = 0; m < (TJ * 3) / 64; ++m) {
            const int f = lane + 64 * m;
            tileF[(f / 3) * 4 + (f % 3)] = g[f];
        }
        // wave-private quadrant; lanes are lockstep within the wave and the
        // compiler inserts lgkmcnt waits for the write->read dependence.

        const int jg0 = jbase + t0;
        // this block's 64 points (i0..i0+63, 64-aligned) lie in this 256-j
        // tile iff the 256-aligned ranges match -> wave-uniform condition
        if ((i0 >> 8) == (jg0 >> 8)) {
            process_tile<true >(&tile[w][0], jg0, i, mx, my, mz, knn);
        } else {
            process_tile<false>(&tile[w][0], jg0, i, mx, my, mz, knn);
        }
    }

    // ---- publish sorted list + sentinel
#pragma unroll
    for (int q = 0; q < K_; ++q) lst[w][lane][q] = knn[q];
    lst[w][lane][K_] = HUGE_D;
    __syncthreads();

    // ---- 4-way merge of sorted lists, one thread per point (wave 0)
    if (threadIdx.x < PTS) {
        const int l = threadIdx.x;
        int p0 = 0, p1 = 0, p2 = 0, p3 = 0;
        float h0 = lst[0][l][0], h1 = lst[1][l][0];
        float h2 = lst[2][l][0], h3 = lst[3][l][0];
        float s = 0.0f;
#pragma unroll
        for (int step = 0; step < K_; ++step) {
            const float m = fminf(fminf(h0, h1), fminf(h2, h3));
            s += m;
            if (h0 == m)      { h0 = lst[0][l][++p0]; }
            else if (h1 == m) { h1 = lst[1][l][++p1]; }
            else if (h2 == m) { h2 = lst[2][l][++p2]; }
            else              { h3 = lst[3][l][++p3]; }
        }
        knn_out[b * N_ + i0 + l] = s * (1.0f / (float)K_);
    }
}

// ---------------------------------------------------------------------------
// Block reduction helper (256 threads = 4 waves)
// ---------------------------------------------------------------------------
__device__ __forceinline__ float block_reduce_sum_256(float v, float* sbuf) {
    const int lane = threadIdx.x & 63;
    const int w    = threadIdx.x >> 6;
#pragma unroll
    for (int o = 32; o > 0; o >>= 1) v += __shfl_down(v, o, 64);
    __syncthreads();
    if (lane == 0) sbuf[w] = v;
    __syncthreads();
    return sbuf[0] + sbuf[1] + sbuf[2] + sbuf[3];
}

// ---------------------------------------------------------------------------
// Kernel 2: per-batch mean, std (two-pass), threshold, penalty partial sum.
// ---------------------------------------------------------------------------
__global__ __launch_bounds__(256) void stats_kernel(const float* __restrict__ knn_d,
                                                    float* __restrict__ partial) {
    const int b   = blockIdx.x;
    const int tid = threadIdx.x;
    const float* __restrict__ x = knn_d + (size_t)b * N_;

    __shared__ float sbuf[4];

    float v[16];
    float s = 0.0f;
#pragma unroll
    for (int t = 0; t < 16; ++t) {
        v[t] = x[tid + t * 256];
        s += v[t];
    }
    const float total = block_reduce_sum_256(s, sbuf);
    const float mu = total * (1.0f / (float)N_);

    float vs = 0.0f;
#pragma unroll
    for (int t = 0; t < 16; ++t) {
        const float d = v[t] - mu;
        vs += d * d;
    }
    const float var    = block_reduce_sum_256(vs, sbuf) * (1.0f / (float)N_);
    const float thresh = mu + ALPHA_ * sqrtf(var);

    float p = 0.0f;
#pragma unroll
    for (int t = 0; t < 16; ++t) {
        if (v[t] > thresh) p += v[t];
    }
    const float psum = block_reduce_sum_256(p, sbuf);
    if (tid == 0) partial[b] = psum;
}

// ---------------------------------------------------------------------------
// Kernel 3: final scalar = sum(partial) / (B*N)
// ---------------------------------------------------------------------------
__global__ void final_kernel(const float* __restrict__ partial,
                             float* __restrict__ out) {
    if (threadIdx.x == 0) {
        float s = 0.0f;
#pragma unroll
        for (int b = 0; b < B_; ++b) s += partial[b];
        out[0] = s / (float)(B_ * N_);
    }
}

extern "C" void kernel_launch(void* const* d_in, const int* in_sizes, int n_in,
                              void* d_out, int out_size, void* d_ws, size_t ws_size,
                              hipStream_t stream) {
    const float* pcs = (const float*)d_in[0];
    float* out = (float*)d_out;

    float* knn_d   = (float*)d_ws;           // B*N floats = 256 KB
    float* partial = knn_d + B_ * N_;        // B floats

    knn_kernel<<<B_ * (N_ / PTS), BLK, 0, stream>>>(pcs, knn_d);
    stats_kernel<<<B_, 256, 0, stream>>>(knn_d, partial);
    final_kernel<<<1, 64, 0, stream>>>(partial, out);
}

// Round 5
// 150.766 us; speedup vs baseline: 5.4579x; 1.2519x over previous
//
#include <hip/hip_runtime.h>
#include <math.h>

#define B_ 16
#define N_ 4096
#define K_ 16
#define ALPHA_ 1.05f

#define JSPLIT 4            // j-chunks per point (one wave each)
#define CHUNK (N_ / JSPLIT) // 1024 j's per wave
#define TJ 256              // j-tile staged in LDS per wave
#define PTS 64              // points per block (one per lane)
#define BLK 256             // 4 waves
#define SENT_F 60000.0f     // sentinel > any real sq-dist (~300); exactly representable in f16

typedef float  f2 __attribute__((ext_vector_type(2)));
typedef __fp16 h2 __attribute__((ext_vector_type(2)));   // matches cvt_pkrtz return type

__device__ __forceinline__ h2 pack_rtz(float a, float b) {
    return __builtin_amdgcn_cvt_pkrtz(a, b);   // v_cvt_pkrtz_f16_f32 (monotone)
}
__device__ __forceinline__ h2 h2min(h2 a, h2 b) { return __builtin_elementwise_min(a, b); }
__device__ __forceinline__ h2 h2max(h2 a, h2 b) { return __builtin_elementwise_max(a, b); }

// ---------------------------------------------------------------------------
// Packed bitonic networks: each h2 register carries two independent candidate
// streams (lo/hi), so one v_pk_min/max does 2 compare-exchanges.
// ---------------------------------------------------------------------------
__device__ __forceinline__ void bitonic_sort16h(h2 v[16]) {
#pragma unroll
    for (int k = 2; k <= 16; k <<= 1) {
#pragma unroll
        for (int j = k >> 1; j > 0; j >>= 1) {
#pragma unroll
            for (int i = 0; i < 16; ++i) {
                const int l = i ^ j;
                if (l > i) {
                    const bool up = ((i & k) == 0);   // compile-time
                    const h2 a = v[i], b = v[l];
                    const h2 lo = h2min(a, b), hi = h2max(a, b);
                    v[i] = up ? lo : hi;
                    v[l] = up ? hi : lo;
                }
            }
        }
    }
}

// knn (sorted asc, packed) := lowest 16 of {knn, c} per half; c sorted asc.
__device__ __forceinline__ void merge16h(h2 knn[16], const h2 c[16]) {
#pragma unroll
    for (int i = 0; i < 16; ++i) knn[i] = h2min(knn[i], c[15 - i]);
#pragma unroll
    for (int j = 8; j > 0; j >>= 1) {
#pragma unroll
        for (int i = 0; i < 16; ++i) {
            const int l = i ^ j;
            if (l > i) {
                const h2 a = knn[i], b = knn[l];
                knn[i] = h2min(a, b);
                knn[l] = h2max(a, b);
            }
        }
    }
}

// f32 merge for the once-per-wave lo/hi combine (both sorted asc).
__device__ __forceinline__ void merge16f(float knn[16], const float c[16]) {
#pragma unroll
    for (int i = 0; i < 16; ++i) knn[i] = fminf(knn[i], c[15 - i]);
#pragma unroll
    for (int j = 8; j > 0; j >>= 1) {
#pragma unroll
        for (int i = 0; i < 16; ++i) {
            const int l = i ^ j;
            if (l > i) {
                const float a = knn[i], b = knn[l];
                knn[i] = fminf(a, b);
                knn[l] = fmaxf(a, b);
            }
        }
    }
}

// ---------------------------------------------------------------------------
// Process one 256-j SoA tile: 8 macro-batches of 32 j's. Distances in packed
// f32 (v_pk_fma_f32), keys packed to f16 (cvt_pkrtz), selection packed f16.
// ---------------------------------------------------------------------------
template <bool HAS_SELF>
__device__ __forceinline__ void process_tile(const float4* __restrict__ xs,
                                             const float4* __restrict__ ys,
                                             const float4* __restrict__ zs,
                                             int jg0, int i,
                                             f2 mx2, f2 my2, f2 mz2,
                                             h2 knn[16]) {
#pragma unroll 1
    for (int bb = 0; bb < TJ / 32; ++bb) {
        h2 c[16];
#pragma unroll
        for (int q = 0; q < 8; ++q) {
            const float4 xq = xs[bb * 8 + q];     // uniform -> LDS broadcast
            const float4 yq = ys[bb * 8 + q];
            const float4 zq = zs[bb * 8 + q];
            const f2 xa = {xq.x, xq.y}, xb = {xq.z, xq.w};
            const f2 ya = {yq.x, yq.y}, yb = {yq.z, yq.w};
            const f2 za = {zq.x, zq.y}, zb = {zq.z, zq.w};
            const f2 dxa = mx2 - xa, dxb = mx2 - xb;
            const f2 dya = my2 - ya, dyb = my2 - yb;
            const f2 dza = mz2 - za, dzb = mz2 - zb;
            const f2 da = dxa * dxa + dya * dya + dza * dza;
            const f2 db = dxb * dxb + dyb * dyb + dzb * dzb;
            float a0 = da.x, a1 = da.y, b0 = db.x, b1 = db.y;
            if (HAS_SELF) {
                const int jg = jg0 + bb * 32 + q * 4;
                a0 = (jg + 0 == i) ? SENT_F : a0;
                a1 = (jg + 1 == i) ? SENT_F : a1;
                b0 = (jg + 2 == i) ? SENT_F : b0;
                b1 = (jg + 3 == i) ? SENT_F : b1;
            }
            c[2 * q + 0] = pack_rtz(a0, a1);
            c[2 * q + 1] = pack_rtz(b0, b1);
        }
        bitonic_sort16h(c);
        merge16h(knn, c);
    }
}

// ---------------------------------------------------------------------------
// Kernel 1: per-point mean of 16 smallest non-self squared distances.
// Block = 256 threads = 4 waves. Wave w handles points [i0, i0+64) against
// j-chunk w (1024 j's). Fully branch-free packed-f16 bitonic selection.
// ---------------------------------------------------------------------------
__global__ __launch_bounds__(BLK, 4) void knn_kernel(const float* __restrict__ pcs,
                                                     float* __restrict__ knn_out) {
    __shared__ float4 s[JSPLIT][3][TJ / 4];      // SoA x/y/z, 12 KB
    __shared__ float  lst[JSPLIT][PTS][K_ + 1];  // 17.4 KB, +1 pad

    const int b    = blockIdx.x >> 6;            // 64 blocks per batch
    const int grp  = blockIdx.x & 63;
    const int i0   = grp * PTS;
    const int lane = threadIdx.x & 63;
    const int w    = threadIdx.x >> 6;

    const float* __restrict__ src = pcs + (size_t)b * N_ * 3;

    const int i  = i0 + lane;
    const float mx = src[3 * i + 0];
    const float my = src[3 * i + 1];
    const float mz = src[3 * i + 2];
    const f2 mx2 = {mx, mx}, my2 = {my, my}, mz2 = {mz, mz};

    const h2 sent = {(__fp16)SENT_F, (__fp16)SENT_F};
    h2 knn[K_];
#pragma unroll
    for (int t = 0; t < K_; ++t) knn[t] = sent;

    const int jbase = w * CHUNK;
    float* sf = (float*)&s[w][0][0];

#pragma unroll 1
    for (int t0 = 0; t0 < CHUNK; t0 += TJ) {
        // ---- stage TJ points (768 consecutive floats) into this wave's SoA
        //      quadrant: float f -> point f/3, coord f%3.
        const float* __restrict__ g = src + (size_t)(jbase + t0) * 3;
#pragma unroll
        for (int m = 0; m < (TJ * 3) / 64; ++m) {
            const int f = lane + 64 * m;
            sf[(f % 3) * TJ + (f / 3)] = g[f];
        }
        // wave-private quadrant; lanes lockstep within the wave, compiler
        // inserts lgkmcnt waits for the write->read dependence.

        const int jg0 = jbase + t0;
        if ((i0 >> 8) == (jg0 >> 8)) {
            process_tile<true >(&s[w][0][0], &s[w][1][0], &s[w][2][0],
                                jg0, i, mx2, my2, mz2, knn);
        } else {
            process_tile<false>(&s[w][0][0], &s[w][1][0], &s[w][2][0],
                                jg0, i, mx2, my2, mz2, knn);
        }
    }

    // ---- combine the two packed streams (lo/hi), once per wave
    float lo[K_], hi[K_];
#pragma unroll
    for (int t = 0; t < K_; ++t) { lo[t] = (float)knn[t].x; hi[t] = (float)knn[t].y; }
    merge16f(lo, hi);   // lowest 16 of 32, sorted asc

#pragma unroll
    for (int q = 0; q < K_; ++q) lst[w][lane][q] = lo[q];
    lst[w][lane][K_] = SENT_F;
    __syncthreads();

    // ---- 4-way merge of sorted lists, one thread per point (wave 0)
    if (threadIdx.x < PTS) {
        const int l = threadIdx.x;
        int p0 = 0, p1 = 0, p2 = 0, p3 = 0;
        float h0 = lst[0][l][0], h1 = lst[1][l][0];
        float h2v = lst[2][l][0], h3 = lst[3][l][0];
        float sm = 0.0f;
#pragma unroll
        for (int step = 0; step < K_; ++step) {
            const float m = fminf(fminf(h0, h1), fminf(h2v, h3));
            sm += m;
            if (h0 == m)       { h0 = lst[0][l][++p0]; }
            else if (h1 == m)  { h1 = lst[1][l][++p1]; }
            else if (h2v == m) { h2v = lst[2][l][++p2]; }
            else               { h3 = lst[3][l][++p3]; }
        }
        knn_out[b * N_ + i0 + l] = sm * (1.0f / (float)K_);
    }
}

// ---------------------------------------------------------------------------
// Block reduction helper (256 threads = 4 waves)
// ---------------------------------------------------------------------------
__device__ __forceinline__ float block_reduce_sum_256(float v, float* sbuf) {
    const int lane = threadIdx.x & 63;
    const int w    = threadIdx.x >> 6;
#pragma unroll
    for (int o = 32; o > 0; o >>= 1) v += __shfl_down(v, o, 64);
    __syncthreads();
    if (lane == 0) sbuf[w] = v;
    __syncthreads();
    return sbuf[0] + sbuf[1] + sbuf[2] + sbuf[3];
}

// ---------------------------------------------------------------------------
// Kernel 2: per-batch mean, std (two-pass), threshold, penalty partial sum.
// ---------------------------------------------------------------------------
__global__ __launch_bounds__(256) void stats_kernel(const float* __restrict__ knn_d,
                                                    float* __restrict__ partial) {
    const int b   = blockIdx.x;
    const int tid = threadIdx.x;
    const float* __restrict__ x = knn_d + (size_t)b * N_;

    __shared__ float sbuf[4];

    float v[16];
    float s = 0.0f;
#pragma unroll
    for (int t = 0; t < 16; ++t) {
        v[t] = x[tid + t * 256];
        s += v[t];
    }
    const float total = block_reduce_sum_256(s, sbuf);
    const float mu = total * (1.0f / (float)N_);

    float vs = 0.0f;
#pragma unroll
    for (int t = 0; t < 16; ++t) {
        const float d = v[t] - mu;
        vs += d * d;
    }
    const float var    = block_reduce_sum_256(vs, sbuf) * (1.0f / (float)N_);
    const float thresh = mu + ALPHA_ * sqrtf(var);

    float p = 0.0f;
#pragma unroll
    for (int t = 0; t < 16; ++t) {
        if (v[t] > thresh) p += v[t];
    }
    const float psum = block_reduce_sum_256(p, sbuf);
    if (tid == 0) partial[b] = psum;
}

// ---------------------------------------------------------------------------
// Kernel 3: final scalar = sum(partial) / (B*N)
// ---------------------------------------------------------------------------
__global__ void final_kernel(const float* __restrict__ partial,
                             float* __restrict__ out) {
    if (threadIdx.x == 0) {
        float s = 0.0f;
#pragma unroll
        for (int b = 0; b < B_; ++b) s += partial[b];
        out[0] = s / (float)(B_ * N_);
    }
}

extern "C" void kernel_launch(void* const* d_in, const int* in_sizes, int n_in,
                              void* d_out, int out_size, void* d_ws, size_t ws_size,
                              hipStream_t stream) {
    const float* pcs = (const float*)d_in[0];
    float* out = (float*)d_out;

    float* knn_d   = (float*)d_ws;           // B*N floats = 256 KB
    float* partial = knn_d + B_ * N_;        // B floats

    knn_kernel<<<B_ * (N_ / PTS), BLK, 0, stream>>>(pcs, knn_d);
    stats_kernel<<<B_, 256, 0, stream>>>(knn_d, partial);
    final_kernel<<<1, 64, 0, stream>>>(partial, out);
}

// Round 7
// 138.094 us; speedup vs baseline: 5.9587x; 1.0918x over previous
//
#include <hip/hip_runtime.h>
#include <math.h>

#define B_ 16
#define N_ 4096
#define K_ 16
#define ALPHA_ 1.05f

#define JSPLIT 4            // j-chunks per point (one wave each)
#define CHUNK (N_ / JSPLIT) // 1024 j's per wave
#define TJ 256              // j-tile staged in LDS per wave
#define PTS 64              // points per block (one per lane)
#define BLK 256             // 4 waves
#define SENT_F 60000.0f     // sentinel > any real sq-dist (~300); f16-representable

typedef __fp16 h2 __attribute__((ext_vector_type(2)));

struct H2x4 { h2 v[4]; };   // view of one float4 = 8 fp16 = 4 h2 pairs

__device__ __forceinline__ h2 h2min(h2 a, h2 b) { return __builtin_elementwise_min(a, b); }
__device__ __forceinline__ h2 h2max(h2 a, h2 b) { return __builtin_elementwise_max(a, b); }

// ---------------------------------------------------------------------------
// Batcher odd-even merge sort, n=16, ascending: 63 CE (vs 80 bitonic).
// All indices compile-time -> pure v_pk_min/max_f16, 2 streams per instr.
// ---------------------------------------------------------------------------
__device__ __forceinline__ void oems_sort16h(h2 v[16]) {
#pragma unroll
    for (int p = 1; p < 16; p <<= 1) {
#pragma unroll
        for (int k = p; k >= 1; k >>= 1) {
#pragma unroll
            for (int j = k & (p - 1); j + k < 16; j += 2 * k) {
#pragma unroll
                for (int i = 0; i < k; ++i) {
                    if (i + j + k < 16 &&
                        ((i + j) / (2 * p)) == ((i + j + k) / (2 * p))) {
                        const h2 a = v[i + j], b = v[i + j + k];
                        v[i + j]     = h2min(a, b);
                        v[i + j + k] = h2max(a, b);
                    }
                }
            }
        }
    }
}

// knn (sorted asc, packed) := lowest 16 of {knn, c} per half; c sorted asc.
__device__ __forceinline__ void merge16h(h2 knn[16], const h2 c[16]) {
#pragma unroll
    for (int i = 0; i < 16; ++i) knn[i] = h2min(knn[i], c[15 - i]);
#pragma unroll
    for (int j = 8; j > 0; j >>= 1) {
#pragma unroll
        for (int i = 0; i < 16; ++i) {
            const int l = i ^ j;
            if (l > i) {
                const h2 a = knn[i], b = knn[l];
                knn[i] = h2min(a, b);
                knn[l] = h2max(a, b);
            }
        }
    }
}

// f32 merge for the once-per-wave lo/hi combine (both sorted asc).
__device__ __forceinline__ void merge16f(float knn[16], const float c[16]) {
#pragma unroll
    for (int i = 0; i < 16; ++i) knn[i] = fminf(knn[i], c[15 - i]);
#pragma unroll
    for (int j = 8; j > 0; j >>= 1) {
#pragma unroll
        for (int i = 0; i < 16; ++i) {
            const int l = i ^ j;
            if (l > i) {
                const float a = knn[i], b = knn[l];
                knn[i] = fminf(a, b);
                knn[l] = fmaxf(a, b);
            }
        }
    }
}

// ---------------------------------------------------------------------------
// Process one 256-j f16-SoA tile: 8 macro-batches of 32 j's. Distances in
// packed f16 (v_pk_sub/fma_f16), selection packed f16.
// ---------------------------------------------------------------------------
template <bool HAS_SELF>
__device__ __forceinline__ void process_tile(const float4* __restrict__ xs4,
                                             const float4* __restrict__ ys4,
                                             const float4* __restrict__ zs4,
                                             int jg0, int i,
                                             h2 qx, h2 qy, h2 qz,
                                             h2 knn[16]) {
#pragma unroll 1
    for (int bb = 0; bb < TJ / 32; ++bb) {
        h2 c[16];
#pragma unroll
        for (int r = 0; r < 4; ++r) {
            const H2x4 hx = __builtin_bit_cast(H2x4, xs4[bb * 4 + r]); // b128 broadcast
            const H2x4 hy = __builtin_bit_cast(H2x4, ys4[bb * 4 + r]);
            const H2x4 hz = __builtin_bit_cast(H2x4, zs4[bb * 4 + r]);
#pragma unroll
            for (int t = 0; t < 4; ++t) {
                const h2 dx = qx - hx.v[t];
                const h2 dy = qy - hy.v[t];
                const h2 dz = qz - hz.v[t];
                h2 d = dx * dx + dy * dy + dz * dz;
                if (HAS_SELF) {
                    const int j0 = jg0 + bb * 32 + r * 8 + 2 * t;
                    if (j0 == i)     d.x = (__fp16)SENT_F;
                    if (j0 + 1 == i) d.y = (__fp16)SENT_F;
                }
                c[r * 4 + t] = d;
            }
        }
        oems_sort16h(c);
        merge16h(knn, c);
    }
}

// ---------------------------------------------------------------------------
// Kernel 1: per-point mean of 16 smallest non-self squared distances.
// Block = 256 threads = 4 waves. Wave w handles points [i0, i0+64) against
// j-chunk w (1024 j's). Candidates staged in LDS as f16 SoA pairs.
// ---------------------------------------------------------------------------
__global__ __launch_bounds__(BLK, 4) void knn_kernel(const float* __restrict__ pcs,
                                                     float* __restrict__ knn_out) {
    __shared__ float4 s[JSPLIT][3][TJ / 8];      // f16 SoA x/y/z, 6 KB
    __shared__ float  lst[JSPLIT][PTS][K_ + 1];  // 17.4 KB, +1 pad

    const int b    = blockIdx.x >> 6;            // 64 blocks per batch
    const int grp  = blockIdx.x & 63;
    const int i0   = grp * PTS;
    const int lane = threadIdx.x & 63;
    const int w    = threadIdx.x >> 6;

    const float* __restrict__ src = pcs + (size_t)b * N_ * 3;

    const int i  = i0 + lane;
    const __fp16 qxh = (__fp16)src[3 * i + 0];   // RTN, same grid as candidates
    const __fp16 qyh = (__fp16)src[3 * i + 1];
    const __fp16 qzh = (__fp16)src[3 * i + 2];
    const h2 qx = {qxh, qxh}, qy = {qyh, qyh}, qz = {qzh, qzh};

    const h2 sent = {(__fp16)SENT_F, (__fp16)SENT_F};
    h2 knn[K_];
#pragma unroll
    for (int t = 0; t < K_; ++t) knn[t] = sent;

    const int jbase = w * CHUNK;
    h2* sxw = (h2*)&s[w][0][0];
    h2* syw = (h2*)&s[w][1][0];
    h2* szw = (h2*)&s[w][2][0];

#pragma unroll 1
    for (int t0 = 0; t0 < CHUNK; t0 += TJ) {
        // ---- stage: lane l loads 4 points (3 float4 = 12 floats), converts
        //      RTN to f16, writes paired h2 SoA. 2-way LDS write alias (free).
        const float4* __restrict__ g4 =
            (const float4*)(src + (size_t)(jbase + t0) * 3);
        const float4 f0 = g4[3 * lane + 0];
        const float4 f1 = g4[3 * lane + 1];
        const float4 f2 = g4[3 * lane + 2];
        sxw[2 * lane + 0] = h2{(__fp16)f0.x, (__fp16)f0.w};
        sxw[2 * lane + 1] = h2{(__fp16)f1.z, (__fp16)f2.y};
        syw[2 * lane + 0] = h2{(__fp16)f0.y, (__fp16)f1.x};
        syw[2 * lane + 1] = h2{(__fp16)f1.w, (__fp16)f2.z};
        szw[2 * lane + 0] = h2{(__fp16)f0.z, (__fp16)f1.y};
        szw[2 * lane + 1] = h2{(__fp16)f2.x, (__fp16)f2.w};
        // wave-private quadrant; lanes lockstep within the wave, compiler
        // inserts lgkmcnt waits for the write->read dependence.

        const int jg0 = jbase + t0;
        if ((i0 >> 8) == (jg0 >> 8)) {
            process_tile<true >(&s[w][0][0], &s[w][1][0], &s[w][2][0],
                                jg0, i, qx, qy, qz, knn);
        } else {
            process_tile<false>(&s[w][0][0], &s[w][1][0], &s[w][2][0],
                                jg0, i, qx, qy, qz, knn);
        }
    }

    // ---- combine the two packed streams (lo/hi), once per wave
    float lo[K_], hi[K_];
#pragma unroll
    for (int t = 0; t < K_; ++t) { lo[t] = (float)knn[t].x; hi[t] = (float)knn[t].y; }
    merge16f(lo, hi);   // lowest 16 of 32, sorted asc

#pragma unroll
    for (int q = 0; q < K_; ++q) lst[w][lane][q] = lo[q];
    lst[w][lane][K_] = SENT_F;
    __syncthreads();

    // ---- 4-way merge of sorted lists, one thread per point (wave 0)
    if (threadIdx.x < PTS) {
        const int l = threadIdx.x;
        int p0 = 0, p1 = 0, p2 = 0, p3 = 0;
        float h0 = lst[0][l][0], h1 = lst[1][l][0];
        float h2v = lst[2][l][0], h3 = lst[3][l][0];
        float sm = 0.0f;
#pragma unroll
        for (int step = 0; step < K_; ++step) {
            const float m = fminf(fminf(h0, h1), fminf(h2v, h3));
            sm += m;
            if (h0 == m)       { h0 = lst[0][l][++p0]; }
            else if (h1 == m)  { h1 = lst[1][l][++p1]; }
            else if (h2v == m) { h2v = lst[2][l][++p2]; }
            else               { h3 = lst[3][l][++p3]; }
        }
        knn_out[b * N_ + i0 + l] = sm * (1.0f / (float)K_);
    }
}

// ---------------------------------------------------------------------------
// Block reduction helper (256 threads = 4 waves)
// ---------------------------------------------------------------------------
__device__ __forceinline__ float block_reduce_sum_256(float v, float* sbuf) {
    const int lane = threadIdx.x & 63;
    const int w    = threadIdx.x >> 6;
#pragma unroll
    for (int o = 32; o > 0; o >>= 1) v += __shfl_down(v, o, 64);
    __syncthreads();
    if (lane == 0) sbuf[w] = v;
    __syncthreads();
    return sbuf[0] + sbuf[1] + sbuf[2] + sbuf[3];
}

// ---------------------------------------------------------------------------
// Kernel 2: per-batch mean, std (two-pass), threshold, penalty partial sum,
// fused final: atomicAdd of scaled penalty into out[0] (memset to 0 first).
// ---------------------------------------------------------------------------
__global__ __launch_bounds__(256) void stats_kernel(const float* __restrict__ knn_d,
                                                    float* __restrict__ out) {
    const int b   = blockIdx.x;
    const int tid = threadIdx.x;
    const float* __restrict__ x = knn_d + (size_t)b * N_;

    __shared__ float sbuf[4];

    float v[16];
    float s = 0.0f;
#pragma unroll
    for (int t = 0; t < 16; ++t) {
        v[t] = x[tid + t * 256];
        s += v[t];
    }
    const float total = block_reduce_sum_256(s, sbuf);
    const float mu = total * (1.0f / (float)N_);

    float vs = 0.0f;
#pragma unroll
    for (int t = 0; t < 16; ++t) {
        const float d = v[t] - mu;
        vs += d * d;
    }
    const float var    = block_reduce_sum_256(vs, sbuf) * (1.0f / (float)N_);
    const float thresh = mu + ALPHA_ * sqrtf(var);

    float p = 0.0f;
#pragma unroll
    for (int t = 0; t < 16; ++t) {
        if (v[t] > thresh) p += v[t];
    }
    const float psum = block_reduce_sum_256(p, sbuf);
    if (tid == 0) atomicAdd(out, psum * (1.0f / (float)(B_ * N_)));
}

extern "C" void kernel_launch(void* const* d_in, const int* in_sizes, int n_in,
                              void* d_out, int out_size, void* d_ws, size_t ws_size,
                              hipStream_t stream) {
    const float* pcs = (const float*)d_in[0];
    float* out = (float*)d_out;

    float* knn_d = (float*)d_ws;             // B*N floats = 256 KB

    (void)hipMemsetAsync(out, 0, sizeof(float), stream);
    knn_kernel<<<B_ * (N_ / PTS), BLK, 0, stream>>>(pcs, knn_d);
    stats_kernel<<<B_, 256, 0, stream>>>(knn_d, out);
}

// Round 8
// 134.795 us; speedup vs baseline: 6.1046x; 1.0245x over previous
//
#include <hip/hip_runtime.h>
#include <math.h>

#define B_ 16
#define N_ 4096
#define K_ 16
#define ALPHA_ 1.05f

#define JSPLIT 4            // j-chunks per point (one wave each)
#define CHUNK (N_ / JSPLIT) // 1024 j's per wave
#define TJ 256              // j-tile staged in LDS per wave
#define PTS 64              // points per block (one per lane)
#define BLK 256             // 4 waves
#define SENT_F 60000.0f     // sentinel > any real sq-dist (~300); f16-representable

typedef __fp16 h2 __attribute__((ext_vector_type(2)));

struct H2x4 { h2 v[4]; };   // view of one float4 = 8 fp16 = 4 h2 pairs

// ---------------------------------------------------------------------------
// Guaranteed-packed f16 ops via inline asm (VOP3P). Compiler was scalarizing
// the __builtin_elementwise path (~3x instr bloat, round-7 counters).
// ---------------------------------------------------------------------------
__device__ __forceinline__ h2 h2min(h2 a, h2 b) {
    unsigned int ua = __builtin_bit_cast(unsigned int, a);
    unsigned int ub = __builtin_bit_cast(unsigned int, b);
    unsigned int r;
    asm("v_pk_min_f16 %0, %1, %2" : "=v"(r) : "v"(ua), "v"(ub));
    return __builtin_bit_cast(h2, r);
}
__device__ __forceinline__ h2 h2max(h2 a, h2 b) {
    unsigned int ua = __builtin_bit_cast(unsigned int, a);
    unsigned int ub = __builtin_bit_cast(unsigned int, b);
    unsigned int r;
    asm("v_pk_max_f16 %0, %1, %2" : "=v"(r) : "v"(ua), "v"(ub));
    return __builtin_bit_cast(h2, r);
}
__device__ __forceinline__ h2 h2add(h2 a, h2 b) {
    unsigned int ua = __builtin_bit_cast(unsigned int, a);
    unsigned int ub = __builtin_bit_cast(unsigned int, b);
    unsigned int r;
    asm("v_pk_add_f16 %0, %1, %2" : "=v"(r) : "v"(ua), "v"(ub));
    return __builtin_bit_cast(h2, r);
}
__device__ __forceinline__ h2 h2mul(h2 a, h2 b) {
    unsigned int ua = __builtin_bit_cast(unsigned int, a);
    unsigned int ub = __builtin_bit_cast(unsigned int, b);
    unsigned int r;
    asm("v_pk_mul_f16 %0, %1, %2" : "=v"(r) : "v"(ua), "v"(ub));
    return __builtin_bit_cast(h2, r);
}
__device__ __forceinline__ h2 h2fma(h2 a, h2 b, h2 c) {
    unsigned int ua = __builtin_bit_cast(unsigned int, a);
    unsigned int ub = __builtin_bit_cast(unsigned int, b);
    unsigned int uc = __builtin_bit_cast(unsigned int, c);
    unsigned int r;
    asm("v_pk_fma_f16 %0, %1, %2, %3" : "=v"(r) : "v"(ua), "v"(ub), "v"(uc));
    return __builtin_bit_cast(h2, r);
}

// ---------------------------------------------------------------------------
// Batcher odd-even merge sort, n=16, ascending: 63 CE, 2 streams per instr.
// ---------------------------------------------------------------------------
__device__ __forceinline__ void oems_sort16h(h2 v[16]) {
#pragma unroll
    for (int p = 1; p < 16; p <<= 1) {
#pragma unroll
        for (int k = p; k >= 1; k >>= 1) {
#pragma unroll
            for (int j = k & (p - 1); j + k < 16; j += 2 * k) {
#pragma unroll
                for (int i = 0; i < k; ++i) {
                    if (i + j + k < 16 &&
                        ((i + j) / (2 * p)) == ((i + j + k) / (2 * p))) {
                        const h2 a = v[i + j], b = v[i + j + k];
                        v[i + j]     = h2min(a, b);
                        v[i + j + k] = h2max(a, b);
                    }
                }
            }
        }
    }
}

// knn (sorted asc, packed) := lowest 16 of {knn, c} per half; c sorted asc.
__device__ __forceinline__ void merge16h(h2 knn[16], const h2 c[16]) {
#pragma unroll
    for (int i = 0; i < 16; ++i) knn[i] = h2min(knn[i], c[15 - i]);
#pragma unroll
    for (int j = 8; j > 0; j >>= 1) {
#pragma unroll
        for (int i = 0; i < 16; ++i) {
            const int l = i ^ j;
            if (l > i) {
                const h2 a = knn[i], b = knn[l];
                knn[i] = h2min(a, b);
                knn[l] = h2max(a, b);
            }
        }
    }
}

// f32 merge for the once-per-wave lo/hi combine (both sorted asc).
__device__ __forceinline__ void merge16f(float knn[16], const float c[16]) {
#pragma unroll
    for (int i = 0; i < 16; ++i) knn[i] = fminf(knn[i], c[15 - i]);
#pragma unroll
    for (int j = 8; j > 0; j >>= 1) {
#pragma unroll
        for (int i = 0; i < 16; ++i) {
            const int l = i ^ j;
            if (l > i) {
                const float a = knn[i], b = knn[l];
                knn[i] = fminf(a, b);
                knn[l] = fmaxf(a, b);
            }
        }
    }
}

// ---------------------------------------------------------------------------
// Process one 256-j f16-SoA tile (coords stored NEGATED): 8 batches of 32 j.
// dx = q + (-x) -> v_pk_add; d = dx*dx; d += dy*dy; d += dz*dz (pk_fma).
// ---------------------------------------------------------------------------
template <bool HAS_SELF>
__device__ __forceinline__ void process_tile(const float4* __restrict__ xs4,
                                             const float4* __restrict__ ys4,
                                             const float4* __restrict__ zs4,
                                             int jg0, int i,
                                             h2 qx, h2 qy, h2 qz,
                                             h2 knn[16]) {
#pragma unroll 1
    for (int bb = 0; bb < TJ / 32; ++bb) {
        h2 c[16];
#pragma unroll
        for (int r = 0; r < 4; ++r) {
            const H2x4 hx = __builtin_bit_cast(H2x4, xs4[bb * 4 + r]); // b128 broadcast
            const H2x4 hy = __builtin_bit_cast(H2x4, ys4[bb * 4 + r]);
            const H2x4 hz = __builtin_bit_cast(H2x4, zs4[bb * 4 + r]);
#pragma unroll
            for (int t = 0; t < 4; ++t) {
                const h2 dx = h2add(qx, hx.v[t]);
                const h2 dy = h2add(qy, hy.v[t]);
                const h2 dz = h2add(qz, hz.v[t]);
                h2 d = h2mul(dx, dx);
                d = h2fma(dy, dy, d);
                d = h2fma(dz, dz, d);
                if (HAS_SELF) {
                    const int j0 = jg0 + bb * 32 + r * 8 + 2 * t;
                    if (j0 == i)     d.x = (__fp16)SENT_F;
                    if (j0 + 1 == i) d.y = (__fp16)SENT_F;
                }
                c[r * 4 + t] = d;
            }
        }
        oems_sort16h(c);
        merge16h(knn, c);
    }
}

// ---------------------------------------------------------------------------
// Kernel 1: per-point mean of 16 smallest non-self squared distances.
// Block = 256 threads = 4 waves. Wave w handles points [i0, i0+64) against
// j-chunk w (1024 j's). Candidates staged in LDS as negated f16 SoA pairs.
// ---------------------------------------------------------------------------
__global__ __launch_bounds__(BLK, 4) void knn_kernel(const float* __restrict__ pcs,
                                                     float* __restrict__ knn_out) {
    __shared__ float4 s[JSPLIT][3][TJ / 8];      // f16 SoA x/y/z, 6 KB
    __shared__ float  lst[JSPLIT][PTS][K_ + 1];  // 17.4 KB, +1 pad

    const int b    = blockIdx.x >> 6;            // 64 blocks per batch
    const int grp  = blockIdx.x & 63;
    const int i0   = grp * PTS;
    const int lane = threadIdx.x & 63;
    const int w    = threadIdx.x >> 6;

    const float* __restrict__ src = pcs + (size_t)b * N_ * 3;

    const int i  = i0 + lane;
    const __fp16 qxh = (__fp16)src[3 * i + 0];   // RTN, same grid as candidates
    const __fp16 qyh = (__fp16)src[3 * i + 1];
    const __fp16 qzh = (__fp16)src[3 * i + 2];
    const h2 qx = {qxh, qxh}, qy = {qyh, qyh}, qz = {qzh, qzh};

    const h2 sent = {(__fp16)SENT_F, (__fp16)SENT_F};
    h2 knn[K_];
#pragma unroll
    for (int t = 0; t < K_; ++t) knn[t] = sent;

    const int jbase = w * CHUNK;
    h2* sxw = (h2*)&s[w][0][0];
    h2* syw = (h2*)&s[w][1][0];
    h2* szw = (h2*)&s[w][2][0];

#pragma unroll 1
    for (int t0 = 0; t0 < CHUNK; t0 += TJ) {
        // ---- stage: lane l loads 4 points (3 float4 = 12 floats), converts
        //      NEGATED (RTN) to f16, writes paired h2 SoA.
        const float4* __restrict__ g4 =
            (const float4*)(src + (size_t)(jbase + t0) * 3);
        const float4 f0 = g4[3 * lane + 0];
        const float4 f1 = g4[3 * lane + 1];
        const float4 f2 = g4[3 * lane + 2];
        sxw[2 * lane + 0] = h2{(__fp16)(-f0.x), (__fp16)(-f0.w)};
        sxw[2 * lane + 1] = h2{(__fp16)(-f1.z), (__fp16)(-f2.y)};
        syw[2 * lane + 0] = h2{(__fp16)(-f0.y), (__fp16)(-f1.x)};
        syw[2 * lane + 1] = h2{(__fp16)(-f1.w), (__fp16)(-f2.z)};
        szw[2 * lane + 0] = h2{(__fp16)(-f0.z), (__fp16)(-f1.y)};
        szw[2 * lane + 1] = h2{(__fp16)(-f2.x), (__fp16)(-f2.w)};
        // wave-private quadrant; lanes lockstep within the wave, compiler
        // inserts lgkmcnt waits for the write->read dependence.

        const int jg0 = jbase + t0;
        if ((i0 >> 8) == (jg0 >> 8)) {
            process_tile<true >(&s[w][0][0], &s[w][1][0], &s[w][2][0],
                                jg0, i, qx, qy, qz, knn);
        } else {
            process_tile<false>(&s[w][0][0], &s[w][1][0], &s[w][2][0],
                                jg0, i, qx, qy, qz, knn);
        }
    }

    // ---- combine the two packed streams (lo/hi), once per wave
    float lo[K_], hi[K_];
#pragma unroll
    for (int t = 0; t < K_; ++t) { lo[t] = (float)knn[t].x; hi[t] = (float)knn[t].y; }
    merge16f(lo, hi);   // lowest 16 of 32, sorted asc

#pragma unroll
    for (int q = 0; q < K_; ++q) lst[w][lane][q] = lo[q];
    lst[w][lane][K_] = SENT_F;
    __syncthreads();

    // ---- 4-way merge of sorted lists, one thread per point (wave 0)
    if (threadIdx.x < PTS) {
        const int l = threadIdx.x;
        int p0 = 0, p1 = 0, p2 = 0, p3 = 0;
        float h0 = lst[0][l][0], h1 = lst[1][l][0];
        float h2v = lst[2][l][0], h3 = lst[3][l][0];
        float sm = 0.0f;
#pragma unroll
        for (int step = 0; step < K_; ++step) {
            const float m = fminf(fminf(h0, h1), fminf(h2v, h3));
            sm += m;
            if (h0 == m)       { h0 = lst[0][l][++p0]; }
            else if (h1 == m)  { h1 = lst[1][l][++p1]; }
            else if (h2v == m) { h2v = lst[2][l][++p2]; }
            else               { h3 = lst[3][l][++p3]; }
        }
        knn_out[b * N_ + i0 + l] = sm * (1.0f / (float)K_);
    }
}

// ---------------------------------------------------------------------------
// Block reduction helper (256 threads = 4 waves)
// ---------------------------------------------------------------------------
__device__ __forceinline__ float block_reduce_sum_256(float v, float* sbuf) {
    const int lane = threadIdx.x & 63;
    const int w    = threadIdx.x >> 6;
#pragma unroll
    for (int o = 32; o > 0; o >>= 1) v += __shfl_down(v, o, 64);
    __syncthreads();
    if (lane == 0) sbuf[w] = v;
    __syncthreads();
    return sbuf[0] + sbuf[1] + sbuf[2] + sbuf[3];
}

// ---------------------------------------------------------------------------
// Kernel 2: per-batch mean, std (two-pass), threshold, penalty partial sum,
// fused final: atomicAdd of scaled penalty into out[0] (memset to 0 first).
// ---------------------------------------------------------------------------
__global__ __launch_bounds__(256) void stats_kernel(const float* __restrict__ knn_d,
                                                    float* __restrict__ out) {
    const int b   = blockIdx.x;
    const int tid = threadIdx.x;
    const float* __restrict__ x = knn_d + (size_t)b * N_;

    __shared__ float sbuf[4];

    float v[16];
    float s = 0.0f;
#pragma unroll
    for (int t = 0; t < 16; ++t) {
        v[t] = x[tid + t * 256];
        s += v[t];
    }
    const float total = block_reduce_sum_256(s, sbuf);
    const float mu = total * (1.0f / (float)N_);

    float vs = 0.0f;
#pragma unroll
    for (int t = 0; t < 16; ++t) {
        const float d = v[t] - mu;
        vs += d * d;
    }
    const float var    = block_reduce_sum_256(vs, sbuf) * (1.0f / (float)N_);
    const float thresh = mu + ALPHA_ * sqrtf(var);

    float p = 0.0f;
#pragma unroll
    for (int t = 0; t < 16; ++t) {
        if (v[t] > thresh) p += v[t];
    }
    const float psum = block_reduce_sum_256(p, sbuf);
    if (tid == 0) atomicAdd(out, psum * (1.0f / (float)(B_ * N_)));
}

extern "C" void kernel_launch(void* const* d_in, const int* in_sizes, int n_in,
                              void* d_out, int out_size, void* d_ws, size_t ws_size,
                              hipStream_t stream) {
    const float* pcs = (const float*)d_in[0];
    float* out = (float*)d_out;

    float* knn_d = (float*)d_ws;             // B*N floats = 256 KB

    (void)hipMemsetAsync(out, 0, sizeof(float), stream);
    knn_kernel<<<B_ * (N_ / PTS), BLK, 0, stream>>>(pcs, knn_d);
    stats_kernel<<<B_, 256, 0, stream>>>(knn_d, out);
}